// Round 8
// baseline (383.257 us; speedup 1.0000x reference)
//
#include <hip/hip_runtime.h>

#define QN 512
#define TN 256
#define INFV 1000000000.0f // matches jnp.float32(1e9)

typedef unsigned long long u64;
typedef float f32x2 __attribute__((ext_vector_type(2)));

// per-lane bit of a wave-uniform 64-bit mask (cndmask with SGPR-pair mask)
#if defined(__has_builtin)
#if __has_builtin(__builtin_amdgcn_inverse_ballot_w64)
#define IBAL(m) __builtin_amdgcn_inverse_ballot_w64(m)
#endif
#endif
#ifndef IBAL
#define IBAL(m) ((bool)(((m) >> l) & 1ull))
#endif

// ---------------------------------------------------------------------------
// Cost matrix: C[b][q][t] = |out[b][q].x - tgt[b][t].x| + |out[b][q].y - tgt[b][t].y|
// ---------------------------------------------------------------------------
__global__ __launch_bounds__(256) void cost_kernel(const float2* __restrict__ outputs,
                                                   const float2* __restrict__ targets,
                                                   float* __restrict__ C) {
    const int t = threadIdx.x;
    const int q = blockIdx.x;
    const int b = blockIdx.y;
    float2 o = outputs[b * QN + q];
    float2 g = targets[b * TN + t];
    C[(size_t)(b * QN + q) * TN + t] = fabsf(o.x - g.x) + fabsf(o.y - g.y);
}

__device__ __forceinline__ float readlane_f(float v, int lane) {
    return __builtin_bit_cast(float, __builtin_amdgcn_readlane(__builtin_bit_cast(int, v), lane));
}

template <int CTRL>
__device__ __forceinline__ float dppminf(float x) {
    int o = __builtin_amdgcn_update_dpp(0, __builtin_bit_cast(int, x), CTRL, 0xF, 0xF, true);
    return fminf(x, __builtin_bit_cast(float, o));
}

#define K8(X) X(0) X(1) X(2) X(3) X(4) X(5) X(6) X(7)
// pairs: pair q holds columns k=2q (.x) and k=2q+1 (.y); column j = l + 64*k
#define P4(X) X(0, 0, 1) X(1, 2, 3) X(2, 4, 5) X(3, 6, 7)

// ---------------------------------------------------------------------------
// Jonker-Volgenant Hungarian, one wave per batch, zero LDS, all-register.
// VOP3P packed-f32 arithmetic, byte-packed p, SALU matched-mask termination.
// Bit-exact FP trajectory vs the JAX reference.
// ---------------------------------------------------------------------------
__global__ __launch_bounds__(64, 1) void hung_kernel(const float2* __restrict__ outputs,
                                                     const float2* __restrict__ targets,
                                                     float* __restrict__ out_row,
                                                     float* __restrict__ out_col) {
    const int b = blockIdx.x;
    const int l = threadIdx.x;   // lane 0..63

    // row-distributed state: row r = l + 64*s; slot s -> pair s>>1, half s&1
    f32x2 uP0 = {0.0f, 0.0f}, uP1 = {0.0f, 0.0f}, rfP0, rfP1;
    float tx0, tx1, tx2, tx3, ty0, ty1, ty2, ty3;
    {
        float2 g0 = targets[b * TN + l];
        float2 g1 = targets[b * TN + l + 64];
        float2 g2 = targets[b * TN + l + 128];
        float2 g3 = targets[b * TN + l + 192];
        tx0 = g0.x; ty0 = g0.y; tx1 = g1.x; ty1 = g1.y;
        tx2 = g2.x; ty2 = g2.y; tx3 = g3.x; ty3 = g3.y;
    }

    // column-distributed state
    f32x2 oxP0, oxP1, oxP2, oxP3, oyP0, oyP1, oyP2, oyP3;
    f32x2 vP0, vP1, vP2, vP3, minvP0, minvP1, minvP2, minvP3;
    int way0, way1, way2, way3, way4, way5, way6, way7;
    unsigned pA = 0u, pB = 0u;   // byte-packed p: slots 0-3 / 4-7
#define LOADP(q, ka, kb) { \
        float2 oa = outputs[b * QN + l + 64 * ka]; \
        float2 ob = outputs[b * QN + l + 64 * kb]; \
        oxP##q = (f32x2){oa.x, ob.x}; oyP##q = (f32x2){oa.y, ob.y}; \
        vP##q = (f32x2){0.0f, 0.0f}; \
        way##ka = QN; way##kb = QN; }
    P4(LOADP)

    // matched-column bitmasks (wave-uniform SGPRs)
#define DECLM(k) u64 mm##k = 0ull;
    K8(DECLM)

    for (int i = 0; i < TN; ++i) {
#define INITP(q, ka, kb) minvP##q = (f32x2){INFV, INFV};
        P4(INITP)
#define DECLCM(k) u64 cm##k = 0ull;
        K8(DECLCM)

        // row i: mark used (mask-built rf), fetch row data
        const int irs = i >> 6, irl = i & 63;
        {
            const u64 rbm = 1ull << irl;
            rfP0.x = IBAL((irs == 0) ? rbm : 0ull) ? 1.0f : 0.0f;
            rfP0.y = IBAL((irs == 1) ? rbm : 0ull) ? 1.0f : 0.0f;
            rfP1.x = IBAL((irs == 2) ? rbm : 0ull) ? 1.0f : 0.0f;
            rfP1.y = IBAL((irs == 3) ? rbm : 0ull) ? 1.0f : 0.0f;
        }
        float ui0, txv, tyv;
        {
            f32x2 up = (irs & 2) ? uP1 : uP0;
            ui0 = readlane_f((irs & 1) ? up.y : up.x, irl);
            float ta = (irs & 1) ? tx1 : tx0, tb = (irs & 1) ? tx3 : tx2;
            txv = readlane_f((irs & 2) ? tb : ta, irl);
            float ya = (irs & 1) ? ty1 : ty0, yb = (irs & 1) ? ty3 : ty2;
            tyv = readlane_f((irs & 2) ? yb : ya, irl);
        }

        float dprev = 0.0f;
        int j0s = QN;
        int jfree;
        for (;;) {
            // ---- scan: packed relax of all columns from the current row ----
#define SCANP(q, ka, kb) { \
            f32x2 d1 = oxP##q - txv; \
            f32x2 d2 = oyP##q - tyv; \
            f32x2 cost = __builtin_elementwise_abs(d1) + __builtin_elementwise_abs(d2); \
            f32x2 cur = (cost - ui0) - vP##q; \
            f32x2 tmp = minvP##q - dprev; \
            const u64 bta = __ballot(cur.x < tmp.x) & ~cm##ka; \
            const u64 btb = __ballot(cur.y < tmp.y) & ~cm##kb; \
            minvP##q.x = IBAL(bta) ? cur.x : tmp.x; \
            minvP##q.y = IBAL(btb) ? cur.y : tmp.y; \
            way##ka = IBAL(bta) ? j0s : way##ka; \
            way##kb = IBAL(btb) ? j0s : way##kb; }
            P4(SCANP)

            // ---- value reduce: packed lane tree + 6 DPP levels ----
            f32x2 m01 = __builtin_elementwise_min(minvP0, minvP1);
            f32x2 m23 = __builtin_elementwise_min(minvP2, minvP3);
            f32x2 mp  = __builtin_elementwise_min(m01, m23);
            float lmin = fminf(mp.x, mp.y);
            lmin = dppminf<0x121>(lmin);   // row_ror:1
            lmin = dppminf<0x122>(lmin);   // row_ror:2
            lmin = dppminf<0x124>(lmin);   // row_ror:4
            lmin = dppminf<0x128>(lmin);   // row_ror:8
            lmin = dppminf<0x142>(lmin);   // row_bcast:15
            lmin = dppminf<0x143>(lmin);   // row_bcast:31
            const float delta = readlane_f(lmin, 63);

            // ---- index find: smallest j with minv == delta (first-min) ----
            const u64 e0 = __ballot(minvP0.x == delta);
            const u64 e1 = __ballot(minvP0.y == delta);
            const u64 e2 = __ballot(minvP1.x == delta);
            const u64 e3 = __ballot(minvP1.y == delta);
            const u64 e4 = __ballot(minvP2.x == delta);
            const u64 e5 = __ballot(minvP2.y == delta);
            const u64 e6 = __ballot(minvP3.x == delta);
            const u64 e7 = __ballot(minvP3.y == delta);
            u64 esel = e7; int kb_ = 7;
            esel = e6 ? e6 : esel; kb_ = e6 ? 6 : kb_;
            esel = e5 ? e5 : esel; kb_ = e5 ? 5 : kb_;
            esel = e4 ? e4 : esel; kb_ = e4 ? 4 : kb_;
            esel = e3 ? e3 : esel; kb_ = e3 ? 3 : kb_;
            esel = e2 ? e2 : esel; kb_ = e2 ? 2 : kb_;
            esel = e1 ? e1 : esel; kb_ = e1 ? 1 : kb_;
            esel = e0 ? e0 : esel; kb_ = e0 ? 0 : kb_;
            const int j1s = (kb_ << 6) | (int)__builtin_ctzll(esel);
            const int cslot = j1s >> 6, clane = j1s & 63;

            // ---- dual updates (packed fma/sub; bit-exact vs masked add/sub) ----
            const f32x2 dl2 = {delta, delta};
            uP0 = __builtin_elementwise_fma(rfP0, dl2, uP0);
            uP1 = __builtin_elementwise_fma(rfP1, dl2, uP1);
#define UPDVP(q, ka, kb) { f32x2 vm = vP##q - delta; \
            vP##q.x = IBAL(cm##ka) ? vm.x : vP##q.x; \
            vP##q.y = IBAL(cm##kb) ? vm.y : vP##q.y; }
            P4(UPDVP)
            dprev = delta;

            // ---- termination: SALU matched-bit test ----
            u64 mmsel = mm0;
            mmsel = (cslot == 1) ? mm1 : mmsel;
            mmsel = (cslot == 2) ? mm2 : mmsel;
            mmsel = (cslot == 3) ? mm3 : mmsel;
            mmsel = (cslot == 4) ? mm4 : mmsel;
            mmsel = (cslot == 5) ? mm5 : mmsel;
            mmsel = (cslot == 6) ? mm6 : mmsel;
            mmsel = (cslot == 7) ? mm7 : mmsel;
            if (((mmsel >> clane) & 1ull) == 0ull) { jfree = j1s; break; }

            // ---- i0 = p[j1]: byte extract (2 readlane + SALU) ----
            const unsigned pwA = (unsigned)__builtin_amdgcn_readlane((int)pA, clane);
            const unsigned pwB = (unsigned)__builtin_amdgcn_readlane((int)pB, clane);
            const unsigned pws = (cslot & 4) ? pwB : pwA;
            const int i0s = (int)((pws >> ((cslot & 3) * 8)) & 0xFFu);

            // ---- mark column j1: cm bit + minv := INFV (drift-safe) ----
            const u64 cb = 1ull << clane;
#define MRKC0(k, href) { const u64 mb = (cslot == k) ? cb : 0ull; cm##k |= mb; \
                         href = IBAL(mb) ? INFV : href; }
            MRKC0(0, minvP0.x) MRKC0(1, minvP0.y)
            MRKC0(2, minvP1.x) MRKC0(3, minvP1.y)
            MRKC0(4, minvP2.x) MRKC0(5, minvP2.y)
            MRKC0(6, minvP3.x) MRKC0(7, minvP3.y)

            // ---- next row data + mask-built row mark ----
            const int nrs = i0s >> 6, nrl = i0s & 63;
            {
                f32x2 up = (nrs & 2) ? uP1 : uP0;
                ui0 = readlane_f((nrs & 1) ? up.y : up.x, nrl);
                float ta = (nrs & 1) ? tx1 : tx0, tb = (nrs & 1) ? tx3 : tx2;
                txv = readlane_f((nrs & 2) ? tb : ta, nrl);
                float ya = (nrs & 1) ? ty1 : ty0, yb = (nrs & 1) ? ty3 : ty2;
                tyv = readlane_f((nrs & 2) ? yb : ya, nrl);
            }
            {
                const u64 rbm = 1ull << nrl;
                rfP0.x = IBAL((nrs == 0) ? rbm : 0ull) ? 1.0f : rfP0.x;
                rfP0.y = IBAL((nrs == 1) ? rbm : 0ull) ? 1.0f : rfP0.y;
                rfP1.x = IBAL((nrs == 2) ? rbm : 0ull) ? 1.0f : rfP1.x;
                rfP1.y = IBAL((nrs == 3) ? rbm : 0ull) ? 1.0f : rfP1.y;
            }
            j0s = j1s;
        }

        // ---- augment walk: p[jj] = p[way[jj]] along the chain ----
        {
            int jj = jfree;
            for (;;) {
                const int ws = jj >> 6, wl = jj & 63;
                int wsel;
                {
                    int a0 = (ws & 1) ? way1 : way0, a1 = (ws & 1) ? way3 : way2;
                    int a2 = (ws & 1) ? way5 : way4, a3 = (ws & 1) ? way7 : way6;
                    int b0 = (ws & 2) ? a1 : a0, b1 = (ws & 2) ? a3 : a2;
                    wsel = (ws & 4) ? b1 : b0;
                }
                const int jn = __builtin_amdgcn_readlane(wsel, wl);
                int pn;
                if (jn == QN) pn = i;
                else {
                    const int qs = jn >> 6, ql = jn & 63;
                    const unsigned qwA = (unsigned)__builtin_amdgcn_readlane((int)pA, ql);
                    const unsigned qwB = (unsigned)__builtin_amdgcn_readlane((int)pB, ql);
                    const unsigned qws = (qs & 4) ? qwB : qwA;
                    pn = (int)((qws >> ((qs & 3) * 8)) & 0xFFu);
                }
                // write byte pn into lane wl, slot ws
                const int sh = (ws & 3) * 8;
                const unsigned bm = 0xFFu << sh;
                const unsigned bv = ((unsigned)pn) << sh;
                const u64 lm_ = 1ull << wl;
                const u64 mA_ = (ws < 4) ? lm_ : 0ull;
                const u64 mB_ = (ws < 4) ? 0ull : lm_;
                pA = IBAL(mA_) ? ((pA & ~bm) | bv) : pA;
                pB = IBAL(mB_) ? ((pB & ~bm) | bv) : pB;
                if (jn == QN) break;
                jj = jn;
            }
            const int fs = jfree >> 6;
            const u64 fb = 1ull << (jfree & 63);
#define SETM(k) mm##k = (fs == k) ? (mm##k | fb) : mm##k;
            K8(SETM)
        }
    }

    // ---- emit matched pairs sorted by query index (ballot == mm) ----
    int rank_base = 0;
#define EMIT(k) { const u64 m = mm##k; \
                  const int below = __popcll(m & ((1ull << l) - 1ull)); \
                  if (IBAL(m)) { const int r = rank_base + below; \
                      const unsigned pw = (k < 4) ? pA : pB; \
                      const int pq = (int)((pw >> ((k & 3) * 8)) & 0xFFu); \
                      out_row[b * TN + r] = (float)(l + 64 * k); \
                      out_col[b * TN + r] = (float)pq; } \
                  rank_base += __popcll(m); }
    K8(EMIT)
}

extern "C" void kernel_launch(void* const* d_in, const int* in_sizes, int n_in,
                              void* d_out, int out_size, void* d_ws, size_t ws_size,
                              hipStream_t stream) {
    const float2* outputs = (const float2*)d_in[0];   // [8,512,2] f32
    const float2* targets = (const float2*)d_in[1];   // [8,256,2] f32
    float* out = (float*)d_out;
    float* out_row = out;                 // [8,256] as float
    float* out_col = out + 8 * TN;        // [8,256] as float
    float* C       = out + 2 * 8 * TN;    // [8,512,256] f32

    dim3 gridC(QN, 8);
    cost_kernel<<<gridC, TN, 0, stream>>>(outputs, targets, C);
    hung_kernel<<<8, 64, 0, stream>>>(outputs, targets, out_row, out_col);
}

// Round 10
// 379.812 us; speedup vs baseline: 1.0091x; 1.0091x over previous
//
#include <hip/hip_runtime.h>

#define QN 512
#define TN 256
#define INFV 1000000000.0f // matches jnp.float32(1e9)

typedef unsigned long long u64;

// per-lane bit of a wave-uniform 64-bit mask (cndmask with SGPR-pair mask)
#if defined(__has_builtin)
#if __has_builtin(__builtin_amdgcn_inverse_ballot_w64)
#define IBAL(m) __builtin_amdgcn_inverse_ballot_w64(m)
#endif
#endif
#ifndef IBAL
#define IBAL(m) ((bool)(((m) >> l) & 1ull))
#endif

// ---------------------------------------------------------------------------
// Cost matrix: C[b][q][t] = |out[b][q].x - tgt[b][t].x| + |out[b][q].y - tgt[b][t].y|
// ---------------------------------------------------------------------------
__global__ __launch_bounds__(256) void cost_kernel(const float2* __restrict__ outputs,
                                                   const float2* __restrict__ targets,
                                                   float* __restrict__ C) {
    const int t = threadIdx.x;
    const int q = blockIdx.x;
    const int b = blockIdx.y;
    float2 o = outputs[b * QN + q];
    float2 g = targets[b * TN + t];
    C[(size_t)(b * QN + q) * TN + t] = fabsf(o.x - g.x) + fabsf(o.y - g.y);
}

__device__ __forceinline__ float readlane_f(float v, int lane) {
    return __builtin_bit_cast(float, __builtin_amdgcn_readlane(__builtin_bit_cast(int, v), lane));
}

// DPP min via intrinsic: compiler handles wait-state hazards and fuses to
// v_min_f32_dpp where legal (GCNDPPCombine). DO NOT hand-write DPP asm —
// the hazard recognizer can't see inside asm strings (R9 post-mortem).
template <int CTRL>
__device__ __forceinline__ float dppminf(float x) {
    int o = __builtin_amdgcn_update_dpp(0, __builtin_bit_cast(int, x), CTRL, 0xF, 0xF, true);
    return fminf(x, __builtin_bit_cast(float, o));
}

#define K8(X) X(0) X(1) X(2) X(3) X(4) X(5) X(6) X(7)
#define R4(X) X(0) X(1) X(2) X(3)

// ---------------------------------------------------------------------------
// Jonker-Volgenant Hungarian, one wave per batch, zero LDS, all-register.
// R7 skeleton (scalar named regs) + byte-packed p + SALU mm termination.
// Bit-exact FP trajectory vs the JAX reference.
// ---------------------------------------------------------------------------
__global__ __launch_bounds__(64, 1) void hung_kernel(const float2* __restrict__ outputs,
                                                     const float2* __restrict__ targets,
                                                     float* __restrict__ out_row,
                                                     float* __restrict__ out_col) {
    const int b = blockIdx.x;
    const int l = threadIdx.x;   // lane 0..63

    // row-distributed state: row r = l + 64*s
#define DECLR(s) float tx##s, ty##s, u##s, rf##s;
    R4(DECLR)
#define LOADR(s) { float2 g = targets[b * TN + l + 64 * s]; tx##s = g.x; ty##s = g.y; u##s = 0.0f; }
    R4(LOADR)

    // column-distributed state: col j = l + 64*k; p byte-packed in pA/pB
#define DECLC(k) float ox##k, oy##k, v##k, minv##k; int way##k; const int jc##k = l + 64 * k;
    K8(DECLC)
#define LOADC(k) { float2 o = outputs[b * QN + l + 64 * k]; ox##k = o.x; oy##k = o.y; v##k = 0.0f; \
                   way##k = QN; }
    K8(LOADC)
    unsigned pA = 0u, pB = 0u;   // byte-packed p: slots 0-3 / 4-7

    // matched-column bitmasks (wave-uniform SGPRs)
#define DECLM(k) u64 mm##k = 0ull;
    K8(DECLM)

    for (int i = 0; i < TN; ++i) {
#define INITC(k) minv##k = INFV;
        K8(INITC)
#define DECLCM(k) u64 cm##k = 0ull;
        K8(DECLCM)
        // row-used flags (float, feed fmaf duals); row i marked
#define INITRF(s) rf##s = (i == jc##s) ? 1.0f : 0.0f;
        R4(INITRF)

        // fetch row i data: select-then-readlane
        const int irs = i >> 6, irl = i & 63;
        float ui0, txv, tyv;
        {
            float a0 = (irs & 1) ? u1 : u0,  a1 = (irs & 1) ? u3 : u2;
            float b0 = (irs & 1) ? tx1 : tx0, b1 = (irs & 1) ? tx3 : tx2;
            float c0 = (irs & 1) ? ty1 : ty0, c1 = (irs & 1) ? ty3 : ty2;
            ui0 = readlane_f((irs & 2) ? a1 : a0, irl);
            txv = readlane_f((irs & 2) ? b1 : b0, irl);
            tyv = readlane_f((irs & 2) ? c1 : c0, irl);
        }

        float dprev = 0.0f;
        int j0s = QN;
        int jfree;
        for (;;) {
            // ---- scan: relax all columns; delta-fold; used gated by SALU mask ----
#define SCAN(k) { const float cost = __builtin_fabsf(ox##k - txv) + __builtin_fabsf(oy##k - tyv); \
                  const float cur  = (cost - ui0) - v##k; \
                  const float tmp  = minv##k - dprev; \
                  const u64 bt2 = __ballot(cur < tmp) & ~cm##k; \
                  minv##k = IBAL(bt2) ? cur : tmp; \
                  way##k  = IBAL(bt2) ? j0s : way##k; }
            K8(SCAN)

            // ---- value reduce: exact wave-wide min == delta ----
            float lmin = fminf(fminf(fminf(minv0, minv1), fminf(minv2, minv3)),
                               fminf(fminf(minv4, minv5), fminf(minv6, minv7)));
            lmin = dppminf<0x121>(lmin);   // row_ror:1
            lmin = dppminf<0x122>(lmin);   // row_ror:2
            lmin = dppminf<0x124>(lmin);   // row_ror:4
            lmin = dppminf<0x128>(lmin);   // row_ror:8
            lmin = dppminf<0x142>(lmin);   // row_bcast:15
            lmin = dppminf<0x143>(lmin);   // row_bcast:31
            const float delta = readlane_f(lmin, 63);

            // ---- index find: smallest j with minv == delta (first-min) ----
#define EBAL(k) const u64 e##k = __ballot(minv##k == delta);
            K8(EBAL)
            u64 esel = e7; int kb = 7;
            esel = e6 ? e6 : esel; kb = e6 ? 6 : kb;
            esel = e5 ? e5 : esel; kb = e5 ? 5 : kb;
            esel = e4 ? e4 : esel; kb = e4 ? 4 : kb;
            esel = e3 ? e3 : esel; kb = e3 ? 3 : kb;
            esel = e2 ? e2 : esel; kb = e2 ? 2 : kb;
            esel = e1 ? e1 : esel; kb = e1 ? 1 : kb;
            esel = e0 ? e0 : esel; kb = e0 ? 0 : kb;
            const int j1s = (kb << 6) | (int)__builtin_ctzll(esel);
            const int cslot = j1s >> 6, clane = j1s & 63;

            // ---- dual updates (bit-exact: fmaf flag / gated sub) ----
#define UPDU(s) u##s = fmaf(rf##s, delta, u##s);
            R4(UPDU)
#define UPDV(k) { const float vm = v##k - delta; v##k = IBAL(cm##k) ? vm : v##k; }
            K8(UPDV)
            dprev = delta;

            // ---- termination: SALU matched-bit test ----
            u64 mmsel = mm0;
            mmsel = (cslot == 1) ? mm1 : mmsel;
            mmsel = (cslot == 2) ? mm2 : mmsel;
            mmsel = (cslot == 3) ? mm3 : mmsel;
            mmsel = (cslot == 4) ? mm4 : mmsel;
            mmsel = (cslot == 5) ? mm5 : mmsel;
            mmsel = (cslot == 6) ? mm6 : mmsel;
            mmsel = (cslot == 7) ? mm7 : mmsel;
            if (((mmsel >> clane) & 1ull) == 0ull) { jfree = j1s; break; }

            // ---- i0 = p[j1]: byte extract (2 readlane + SALU) ----
            const unsigned pwA = (unsigned)__builtin_amdgcn_readlane((int)pA, clane);
            const unsigned pwB = (unsigned)__builtin_amdgcn_readlane((int)pB, clane);
            const unsigned pws = (cslot & 4) ? pwB : pwA;
            const int i0s = (int)((pws >> ((cslot & 3) * 8)) & 0xFFu);

            // ---- mark column j1: cm bit + minv := INFV (drift-safe) ----
            const u64 cb = 1ull << clane;
#define MRKC(k) { const u64 mb = (cslot == k) ? cb : 0ull; cm##k |= mb; \
                  minv##k = IBAL(mb) ? INFV : minv##k; }
            K8(MRKC)

            // ---- next row data + row mark ----
            const int nrs = i0s >> 6, nrl = i0s & 63;
            {
                float a0 = (nrs & 1) ? u1 : u0,  a1 = (nrs & 1) ? u3 : u2;
                float b0 = (nrs & 1) ? tx1 : tx0, b1 = (nrs & 1) ? tx3 : tx2;
                float c0 = (nrs & 1) ? ty1 : ty0, c1 = (nrs & 1) ? ty3 : ty2;
                ui0 = readlane_f((nrs & 2) ? a1 : a0, nrl);
                txv = readlane_f((nrs & 2) ? b1 : b0, nrl);
                tyv = readlane_f((nrs & 2) ? c1 : c0, nrl);
            }
#define MARKR(s) rf##s = (i0s == jc##s) ? 1.0f : rf##s;
            R4(MARKR)

            j0s = j1s;
        }

        // ---- augment walk: p[jj] = p[way[jj]] along the chain (byte writes) ----
        {
            int jj = jfree;
            for (;;) {
                const int ws = jj >> 6, wl = jj & 63;
                int wsel;
                {
                    int a0 = (ws & 1) ? way1 : way0, a1 = (ws & 1) ? way3 : way2;
                    int a2 = (ws & 1) ? way5 : way4, a3 = (ws & 1) ? way7 : way6;
                    int b0 = (ws & 2) ? a1 : a0, b1 = (ws & 2) ? a3 : a2;
                    wsel = (ws & 4) ? b1 : b0;
                }
                const int jn = __builtin_amdgcn_readlane(wsel, wl);
                int pn;
                if (jn == QN) pn = i;
                else {
                    const int qs = jn >> 6, ql = jn & 63;
                    const unsigned qwA = (unsigned)__builtin_amdgcn_readlane((int)pA, ql);
                    const unsigned qwB = (unsigned)__builtin_amdgcn_readlane((int)pB, ql);
                    const unsigned qws = (qs & 4) ? qwB : qwA;
                    pn = (int)((qws >> ((qs & 3) * 8)) & 0xFFu);
                }
                // write byte pn into lane wl, slot ws
                const int sh = (ws & 3) * 8;
                const unsigned bm = 0xFFu << sh;
                const unsigned bv = ((unsigned)pn) << sh;
                const u64 lm_ = 1ull << wl;
                const u64 mA_ = (ws < 4) ? lm_ : 0ull;
                const u64 mB_ = (ws < 4) ? 0ull : lm_;
                pA = IBAL(mA_) ? ((pA & ~bm) | bv) : pA;
                pB = IBAL(mB_) ? ((pB & ~bm) | bv) : pB;
                if (jn == QN) break;
                jj = jn;
            }
            const int fs = jfree >> 6;
            const u64 fb = 1ull << (jfree & 63);
#define SETM(k) mm##k = (fs == k) ? (mm##k | fb) : mm##k;
            K8(SETM)
        }
    }

    // ---- emit matched pairs sorted by query index (valid mask == mm) ----
    int rank_base = 0;
#define EMIT(k) { const u64 m = mm##k; \
                  const int below = __popcll(m & ((1ull << l) - 1ull)); \
                  if (IBAL(m)) { const int r = rank_base + below; \
                      const unsigned pw = (k < 4) ? pA : pB; \
                      const int pq = (int)((pw >> ((k & 3) * 8)) & 0xFFu); \
                      out_row[b * TN + r] = (float)jc##k; \
                      out_col[b * TN + r] = (float)pq; } \
                  rank_base += __popcll(m); }
    K8(EMIT)
}

extern "C" void kernel_launch(void* const* d_in, const int* in_sizes, int n_in,
                              void* d_out, int out_size, void* d_ws, size_t ws_size,
                              hipStream_t stream) {
    const float2* outputs = (const float2*)d_in[0];   // [8,512,2] f32
    const float2* targets = (const float2*)d_in[1];   // [8,256,2] f32
    float* out = (float*)d_out;
    float* out_row = out;                 // [8,256] as float
    float* out_col = out + 8 * TN;        // [8,256] as float
    float* C       = out + 2 * 8 * TN;    // [8,512,256] f32

    dim3 gridC(QN, 8);
    cost_kernel<<<gridC, TN, 0, stream>>>(outputs, targets, C);
    hung_kernel<<<8, 64, 0, stream>>>(outputs, targets, out_row, out_col);
}

// Round 11
// 353.601 us; speedup vs baseline: 1.0839x; 1.0741x over previous
//
#include <hip/hip_runtime.h>

#define QN 512
#define TN 256
#define INFV 1000000000.0f // matches jnp.float32(1e9)

typedef unsigned long long u64;

// per-lane bit of a wave-uniform 64-bit mask (cndmask with SGPR-pair mask)
#if defined(__has_builtin)
#if __has_builtin(__builtin_amdgcn_inverse_ballot_w64)
#define IBAL(m) __builtin_amdgcn_inverse_ballot_w64(m)
#endif
#endif
#ifndef IBAL
#define IBAL(m) ((bool)(((m) >> l) & 1ull))
#endif

__device__ __forceinline__ float readlane_f(float v, int lane) {
    return __builtin_bit_cast(float, __builtin_amdgcn_readlane(__builtin_bit_cast(int, v), lane));
}

// DPP min via intrinsic: compiler handles wait-state hazards and fuses to
// v_min_f32_dpp (GCNDPPCombine). Never hand-write DPP asm (R9 post-mortem:
// the hazard recognizer can't see inside asm strings -> stale-register reads).
template <int CTRL>
__device__ __forceinline__ float dppminf(float x) {
    int o = __builtin_amdgcn_update_dpp(0, __builtin_bit_cast(int, x), CTRL, 0xF, 0xF, true);
    return fminf(x, __builtin_bit_cast(float, o));
}

#define K8(X) X(0) X(1) X(2) X(3) X(4) X(5) X(6) X(7)
#define R4(X) X(0) X(1) X(2) X(3)

// ---------------------------------------------------------------------------
// Fused kernel: blocks 0..7 run the Jonker-Volgenant Hungarian (one wave per
// batch, zero LDS, all-register, bit-exact FP trajectory vs JAX reference);
// blocks 8.. compute the cost matrix C concurrently on otherwise-idle CUs.
// ---------------------------------------------------------------------------
__global__ __launch_bounds__(64, 1) void fused_kernel(const float2* __restrict__ outputs,
                                                      const float2* __restrict__ targets,
                                                      float* __restrict__ out_row,
                                                      float* __restrict__ out_col,
                                                      float* __restrict__ C) {
    const int l = threadIdx.x;   // lane 0..63

    if (blockIdx.x >= 8) {
        // ---- cost part: 256 contiguous C elements per block, float4 writes ----
        const int cb = blockIdx.x - 8;          // 0..4095
        const int q  = cb & (QN - 1);           // (cb*256)/256 % 512
        const int b  = cb >> 9;                 // /512
        const float2 o = outputs[b * QN + q];
        const int t0 = l * 4;
        const float2 g0 = targets[b * TN + t0 + 0];
        const float2 g1 = targets[b * TN + t0 + 1];
        const float2 g2 = targets[b * TN + t0 + 2];
        const float2 g3 = targets[b * TN + t0 + 3];
        float4 r;
        r.x = fabsf(o.x - g0.x) + fabsf(o.y - g0.y);
        r.y = fabsf(o.x - g1.x) + fabsf(o.y - g1.y);
        r.z = fabsf(o.x - g2.x) + fabsf(o.y - g2.y);
        r.w = fabsf(o.x - g3.x) + fabsf(o.y - g3.y);
        *reinterpret_cast<float4*>(&C[(size_t)(b * QN + q) * TN + t0]) = r;
        return;
    }

    const int b = blockIdx.x;

    // row-distributed state: row r = l + 64*s
#define DECLR(s) float tx##s, ty##s, u##s, rf##s;
    R4(DECLR)
#define LOADR(s) { float2 g = targets[b * TN + l + 64 * s]; tx##s = g.x; ty##s = g.y; u##s = 0.0f; }
    R4(LOADR)

    // column-distributed state: col j = l + 64*k
#define DECLC(k) float ox##k, oy##k, v##k, minv##k; int way##k, p##k; const int jc##k = l + 64 * k;
    K8(DECLC)
#define LOADC(k) { float2 o = outputs[b * QN + l + 64 * k]; ox##k = o.x; oy##k = o.y; v##k = 0.0f; \
                   p##k = -1; way##k = QN; }
    K8(LOADC)

    for (int i = 0; i < TN; ++i) {
#define INITC(k) minv##k = INFV;
        K8(INITC)
#define DECLCM(k) u64 cm##k = 0ull;
        K8(DECLCM)
        // row-used flags (float, feed fmaf duals); row i marked
#define INITRF(s) rf##s = (i == jc##s) ? 1.0f : 0.0f;
        R4(INITRF)

        // fetch row i data: select-then-readlane
        const int irs = i >> 6, irl = i & 63;
        float ui0, txv, tyv;
        {
            float a0 = (irs & 1) ? u1 : u0,  a1 = (irs & 1) ? u3 : u2;
            float b0 = (irs & 1) ? tx1 : tx0, b1 = (irs & 1) ? tx3 : tx2;
            float c0 = (irs & 1) ? ty1 : ty0, c1 = (irs & 1) ? ty3 : ty2;
            ui0 = readlane_f((irs & 2) ? a1 : a0, irl);
            txv = readlane_f((irs & 2) ? b1 : b0, irl);
            tyv = readlane_f((irs & 2) ? c1 : c0, irl);
        }

        float dprev = 0.0f;
        int j0s = QN;
        int jfree;
        for (;;) {
            // ---- scan: relax all columns; delta-fold; used gated by SALU mask ----
#define SCAN(k) { const float cost = __builtin_fabsf(ox##k - txv) + __builtin_fabsf(oy##k - tyv); \
                  const float cur  = (cost - ui0) - v##k; \
                  const float tmp  = minv##k - dprev; \
                  const u64 bt2 = __ballot(cur < tmp) & ~cm##k; \
                  minv##k = IBAL(bt2) ? cur : tmp; \
                  way##k  = IBAL(bt2) ? j0s : way##k; }
            K8(SCAN)

            // ---- value reduce: exact wave-wide min == delta ----
            // min3-shaped: clang fuses fminf(fminf(a,b),c) -> v_min3_f32 (exact)
            const float t0_ = fminf(fminf(minv0, minv1), minv2);
            const float t1_ = fminf(fminf(minv3, minv4), minv5);
            const float t2_ = fminf(fminf(minv6, minv7), t0_);
            float lmin = fminf(t1_, t2_);
            lmin = dppminf<0x121>(lmin);   // row_ror:1
            lmin = dppminf<0x122>(lmin);   // row_ror:2
            lmin = dppminf<0x124>(lmin);   // row_ror:4
            lmin = dppminf<0x128>(lmin);   // row_ror:8
            lmin = dppminf<0x142>(lmin);   // row_bcast:15
            lmin = dppminf<0x143>(lmin);   // row_bcast:31
            const float delta = readlane_f(lmin, 63);

            // ---- index find: smallest j with minv == delta (first-min) ----
#define EBAL(k) const u64 e##k = __ballot(minv##k == delta);
            K8(EBAL)
            u64 esel = e7; int kb = 7;
            esel = e6 ? e6 : esel; kb = e6 ? 6 : kb;
            esel = e5 ? e5 : esel; kb = e5 ? 5 : kb;
            esel = e4 ? e4 : esel; kb = e4 ? 4 : kb;
            esel = e3 ? e3 : esel; kb = e3 ? 3 : kb;
            esel = e2 ? e2 : esel; kb = e2 ? 2 : kb;
            esel = e1 ? e1 : esel; kb = e1 ? 1 : kb;
            esel = e0 ? e0 : esel; kb = e0 ? 0 : kb;
            const int j1s = (kb << 6) | (int)__builtin_ctzll(esel);
            const int cslot = j1s >> 6, clane = j1s & 63;

            // ---- dual updates (bit-exact: fmaf flag / gated sub) ----
#define UPDU(s) u##s = fmaf(rf##s, delta, u##s);
            R4(UPDU)
#define UPDV(k) { const float vm = v##k - delta; v##k = IBAL(cm##k) ? vm : v##k; }
            K8(UPDV)
            dprev = delta;

            // ---- i0 = p[j1] (select-then-readlane); free column -> done ----
            int psel;
            {
                int a0 = (cslot & 1) ? p1 : p0, a1 = (cslot & 1) ? p3 : p2;
                int a2 = (cslot & 1) ? p5 : p4, a3 = (cslot & 1) ? p7 : p6;
                int b0 = (cslot & 2) ? a1 : a0, b1 = (cslot & 2) ? a3 : a2;
                psel = (cslot & 4) ? b1 : b0;
            }
            const int i0s = __builtin_amdgcn_readlane(psel, clane);
            if (i0s < 0) { jfree = j1s; break; }

            // ---- mark column j1: cm bit + minv := INFV (drift-safe) ----
            const u64 cb_ = 1ull << clane;
#define MRKC(k) { const u64 mb = (cslot == k) ? cb_ : 0ull; cm##k |= mb; \
                  minv##k = IBAL(mb) ? INFV : minv##k; }
            K8(MRKC)

            // ---- next row data + row mark ----
            const int nrs = i0s >> 6, nrl = i0s & 63;
            {
                float a0 = (nrs & 1) ? u1 : u0,  a1 = (nrs & 1) ? u3 : u2;
                float b0 = (nrs & 1) ? tx1 : tx0, b1 = (nrs & 1) ? tx3 : tx2;
                float c0 = (nrs & 1) ? ty1 : ty0, c1 = (nrs & 1) ? ty3 : ty2;
                ui0 = readlane_f((nrs & 2) ? a1 : a0, nrl);
                txv = readlane_f((nrs & 2) ? b1 : b0, nrl);
                tyv = readlane_f((nrs & 2) ? c1 : c0, nrl);
            }
#define MARKR(s) rf##s = (i0s == jc##s) ? 1.0f : rf##s;
            R4(MARKR)

            j0s = j1s;
        }

        // ---- augment walk: p[jj] = p[way[jj]] along the chain ----
        {
            int jj = jfree;
            for (;;) {
                const int ws = jj >> 6, wl = jj & 63;
                int wsel;
                {
                    int a0 = (ws & 1) ? way1 : way0, a1 = (ws & 1) ? way3 : way2;
                    int a2 = (ws & 1) ? way5 : way4, a3 = (ws & 1) ? way7 : way6;
                    int b0 = (ws & 2) ? a1 : a0, b1 = (ws & 2) ? a3 : a2;
                    wsel = (ws & 4) ? b1 : b0;
                }
                const int jn = __builtin_amdgcn_readlane(wsel, wl);
                int pn;
                if (jn == QN) pn = i;
                else {
                    const int qs = jn >> 6, ql = jn & 63;
                    int qsel;
                    {
                        int a0 = (qs & 1) ? p1 : p0, a1 = (qs & 1) ? p3 : p2;
                        int a2 = (qs & 1) ? p5 : p4, a3 = (qs & 1) ? p7 : p6;
                        int b0 = (qs & 2) ? a1 : a0, b1 = (qs & 2) ? a3 : a2;
                        qsel = (qs & 4) ? b1 : b0;
                    }
                    pn = __builtin_amdgcn_readlane(qsel, ql);
                }
#define SETP(k) p##k = (jj == jc##k) ? pn : p##k;
                K8(SETP)
                if (jn == QN) break;
                jj = jn;
            }
        }
    }

    // ---- emit matched pairs sorted by query index ----
    int rank_base = 0;
#define EMIT(k) { const int pq = p##k; const bool valid = pq >= 0; \
                  u64 m = __ballot(valid); \
                  int below = __popcll(m & ((1ull << l) - 1ull)); \
                  if (valid) { int r = rank_base + below; \
                               out_row[b * TN + r] = (float)jc##k; \
                               out_col[b * TN + r] = (float)pq; } \
                  rank_base += __popcll(m); }
    K8(EMIT)
}

extern "C" void kernel_launch(void* const* d_in, const int* in_sizes, int n_in,
                              void* d_out, int out_size, void* d_ws, size_t ws_size,
                              hipStream_t stream) {
    const float2* outputs = (const float2*)d_in[0];   // [8,512,2] f32
    const float2* targets = (const float2*)d_in[1];   // [8,256,2] f32
    float* out = (float*)d_out;
    float* out_row = out;                 // [8,256] as float
    float* out_col = out + 8 * TN;        // [8,256] as float
    float* C       = out + 2 * 8 * TN;    // [8,512,256] f32

    // blocks 0..7: Hungarian solver (one wave per batch)
    // blocks 8..8+4095: cost matrix, 256 elements each, concurrent on idle CUs
    fused_kernel<<<8 + 8 * QN * TN / 256, 64, 0, stream>>>(outputs, targets,
                                                           out_row, out_col, C);
}